// Round 5
// baseline (389.009 us; speedup 1.0000x reference)
//
#include <hip/hip_runtime.h>
#include <hip/hip_bf16.h>

typedef __attribute__((ext_vector_type(8))) __bf16 bf16x8;
typedef __attribute__((ext_vector_type(4))) float f32x4;

#define GLOBAL_CPTR(x) ((__attribute__((address_space(1))) const void*)(x))
#define LDS_PTR(x)     ((__attribute__((address_space(3))) void*)(x))

// ---------------------------------------------------------------------------
// MXFP4 fake-quantize: fp32 -> bf16 (exact representation of dequant values)
// ---------------------------------------------------------------------------
__global__ __launch_bounds__(256) void mxfp4_quant_kernel(
    const float* __restrict__ in, ushort* __restrict__ out, long long n) {
  long long base = ((long long)blockIdx.x * 256 + threadIdx.x) * 4;
  if (base >= n) return;

  float4 v = *reinterpret_cast<const float4*>(in + base);
  float am = fmaxf(fmaxf(fabsf(v.x), fabsf(v.y)), fmaxf(fabsf(v.z), fabsf(v.w)));
  am = fmaxf(am, __shfl_xor(am, 1, 64));
  am = fmaxf(am, __shfl_xor(am, 2, 64));
  am = fmaxf(am, __shfl_xor(am, 4, 64));

  float safe = am > 0.f ? am : 1.f;
  int se = ilogbf(safe) - 2;           // floor(log2(amax)) - E2M1_EMAX
  float scale = ldexpf(1.f, se);
  float inv   = ldexpf(1.f, -se);

  float vv[4] = {v.x, v.y, v.z, v.w};
  ushort o16[4];
#pragma unroll
  for (int j = 0; j < 4; ++j) {
    float val = vv[j] * inv;                 // exact (power-of-2)
    float av = fabsf(val);
    float avc = fmaxf(av, 9.765625e-4f);     // 2^-10 floor
    int e = (int)((__float_as_uint(avc) >> 23) & 0xFF) - 127;  // floor(log2)
    e = e < 0 ? 0 : (e > 2 ? 2 : e);
    float step  = ldexpf(1.f, e - 1);
    float istep = ldexpf(1.f, 1 - e);
    float q = rintf(av * istep) * step;      // round-half-to-even
    q = fminf(q, 6.f);
    float r = copysignf(q * scale, val);     // exact in bf16
    __hip_bfloat16 b = __float2bfloat16(r);
    o16[j] = *reinterpret_cast<ushort*>(&b);
  }
  ushort4 packed = make_ushort4(o16[0], o16[1], o16[2], o16[3]);
  *reinterpret_cast<ushort4*>(out + base) = packed;
}

// ---------------------------------------------------------------------------
// 256x256 bf16 GEMM, 4 FAT waves (2x2, 128x128 out/wave), BK=64, dbuf LDS,
// st_16x32 swizzle, ONE barrier per K-tile, stage issued at iteration top.
// C[M][N] = A[M][K]*B[N][K]^T + bias[N]
// Rationale: per-CU LDS-read demand drops 192->128 KB/K-tile (under the
// 2483-cy MFMA shadow); 1 wave/SIMD saturates the matrix pipe via ILP while
// ds_read/global_load_lds issue in the pipe gaps (counted lgkm by compiler).
// LDS layout (ushort): [buf:32768][op A=0/B=16384][half(128r):8192]
//                      [rowblock(16r):1024][khalf:512][row:32][kcol(swz)]
// ---------------------------------------------------------------------------
#define BM 256
#define BN 256
#define NTHR 256

__global__ __launch_bounds__(NTHR, 1) void mxfp_gemm_kernel(
    const ushort* __restrict__ A, const ushort* __restrict__ B,
    const float* __restrict__ bias, float* __restrict__ C,
    int M, int N, int K) {
  __shared__ ushort lds[65536];  // 128 KiB

  const int tid = threadIdx.x;
  const int l   = tid & 63;
  const int wid = tid >> 6;  // 0..3
  const int wm  = wid >> 1;  // 0..1
  const int wn  = wid & 1;   // 0..1

  const int nwg = gridDim.x;       // multiple of 8
  const int bid = blockIdx.x;
  const int swz = (bid & 7) * (nwg >> 3) + (bid >> 3);
  const int nbn = N / BN;
  const int bm  = swz / nbn;
  const int bn  = swz % nbn;

  // swizzled per-lane ds_read offset (ushorts): row (l&15), kcol swz
  const int laneRd = ((l & 15) << 5) + (((l >> 4) << 3) ^ ((l & 8) ? 16 : 0));
  const int aRd = (wm << 13) + laneRd;            // A half wm
  const int bRd = 16384 + (wn << 13) + laneRd;    // B half wn

  // staging: per-lane inverse-swizzled global source; linear LDS dest.
  // lane l covers row (l>>2) of a 16-row unit, 16B at kcol (l&3)*8 (^16 on row&8).
  const int colSwz = ((l & 3) << 3) ^ ((l & 32) ? 16 : 0);
  const ushort* aU = A + (size_t)(bm * BM + wid * 32 + (l >> 2)) * K + colSwz;
  const ushort* bU = B + (size_t)(bn * BN + wid * 32 + (l >> 2)) * K + colSwz;
  const size_t K16 = (size_t)16 * K;    // 16-row stride
  const size_t K128 = (size_t)128 * K;  // half stride

  f32x4 acc[8][8] = {};  // 256 VGPRs, all static indices

// stage one {op, half H, rowblock wid*2+J, khalf KH} unit of tile at KT
#define STG1(UNITP, OPO, OBUF, H, J, KH, KT)                                    \
  __builtin_amdgcn_global_load_lds(                                             \
      GLOBAL_CPTR((UNITP) + (H) * K128 + (J) * K16 + (KT) + (KH) * 32),         \
      LDS_PTR(lds + (OBUF) + (OPO) + (H) * 8192 + ((wid * 2 + (J)) << 10) +     \
              ((KH) << 9)),                                                     \
      16, 0, 0)

#define STG_ALL(OBUF, KT)                                                       \
  do {                                                                          \
    _Pragma("unroll") for (int h = 0; h < 2; ++h)                               \
      _Pragma("unroll") for (int j = 0; j < 2; ++j)                             \
        _Pragma("unroll") for (int kh = 0; kh < 2; ++kh) {                      \
          STG1(aU, 0, OBUF, h, j, kh, KT);                                      \
          STG1(bU, 16384, OBUF, h, j, kh, KT);                                  \
        }                                                                       \
  } while (0)

// one K-tile: stage next tile (earliest issue), then 2 K-halves of
// {16 ds_read_b128 + 64 MFMA}, then counted-satisfied drain + one barrier.
#define KTILE(BUF, OBUF, KTN)                                                   \
  do {                                                                          \
    STG_ALL(OBUF, KTN);                                                         \
    _Pragma("unroll") for (int kh = 0; kh < 2; ++kh) {                          \
      bf16x8 afr[8], bfr[8];                                                    \
      _Pragma("unroll") for (int mb = 0; mb < 8; ++mb)                          \
        afr[mb] = *(const bf16x8*)(lds + (BUF) + aRd + (mb << 10) + (kh << 9)); \
      _Pragma("unroll") for (int nb = 0; nb < 8; ++nb)                          \
        bfr[nb] = *(const bf16x8*)(lds + (BUF) + bRd + (nb << 10) + (kh << 9)); \
      _Pragma("unroll") for (int mb = 0; mb < 8; ++mb)                          \
        _Pragma("unroll") for (int nb = 0; nb < 8; ++nb)                        \
          acc[mb][nb] = __builtin_amdgcn_mfma_f32_16x16x32_bf16(                \
              afr[mb], bfr[nb], acc[mb][nb], 0, 0, 0);                          \
    }                                                                           \
    asm volatile("s_waitcnt vmcnt(0)" ::: "memory");                            \
    __builtin_amdgcn_s_barrier();                                               \
    asm volatile("" ::: "memory");                                              \
  } while (0)

  // prologue: tile0 -> buf0
  STG_ALL(0, 0);
  asm volatile("s_waitcnt vmcnt(0)" ::: "memory");
  __builtin_amdgcn_s_barrier();
  asm volatile("" ::: "memory");

  const int NKT = K >> 6;  // even
  for (int it = 0; it < (NKT >> 1); ++it) {
    const int t  = it << 1;
    const int k1 = (t + 1) << 6;                                // live
    const int k2 = ((t + 2 < NKT) ? (t + 2) : (NKT - 1)) << 6;  // clamp->dead
    KTILE(0, 32768, k1);
    KTILE(32768, 0, k2);
  }

  // epilogue: C/D layout col=lane&15, row=(lane>>4)*4+reg (m89-verified)
  const int colb = bn * BN + wn * 128 + (l & 15);
  const long long rowb = (long long)bm * BM + wm * 128 + ((l >> 4) << 2);
#pragma unroll
  for (int nb = 0; nb < 8; ++nb) {
    const float bv = bias[colb + nb * 16];
#pragma unroll
    for (int mb = 0; mb < 8; ++mb) {
#pragma unroll
      for (int r = 0; r < 4; ++r) {
        C[(rowb + mb * 16 + r) * N + (colb + nb * 16)] = acc[mb][nb][r] + bv;
      }
    }
  }
}

// ---------------------------------------------------------------------------
extern "C" void kernel_launch(void* const* d_in, const int* in_sizes, int n_in,
                              void* d_out, int out_size, void* d_ws, size_t ws_size,
                              hipStream_t stream) {
  const float* x    = (const float*)d_in[0];  // [B,S,K] = [M,K]
  const float* w    = (const float*)d_in[1];  // [N,K]
  const float* bias = (const float*)d_in[2];  // [N]
  float* out = (float*)d_out;

  const int N = in_sizes[2];
  const int K = in_sizes[1] / N;
  const int M = (int)((long long)in_sizes[0] / K);

  ushort* xq = (ushort*)d_ws;                       // M*K bf16
  ushort* wq = xq + (size_t)M * K;                  // N*K bf16

  const long long nx = (long long)M * K;
  const long long nw = (long long)N * K;

  mxfp4_quant_kernel<<<dim3((unsigned)(nx / 1024)), dim3(256), 0, stream>>>(x, xq, nx);
  mxfp4_quant_kernel<<<dim3((unsigned)(nw / 1024)), dim3(256), 0, stream>>>(w, wq, nw);

  dim3 grid((M / BM) * (N / BN));
  mxfp_gemm_kernel<<<grid, dim3(NTHR), 0, stream>>>(xq, wq, bias, out, M, N, K);
}

// Round 6
// 154.511 us; speedup vs baseline: 2.5177x; 2.5177x over previous
//
#include <hip/hip_runtime.h>
#include <hip/hip_bf16.h>

typedef __attribute__((ext_vector_type(4))) int i32x4;
typedef __attribute__((ext_vector_type(8))) int i32x8;
typedef __attribute__((ext_vector_type(16))) float f32x16;

#define GLOBAL_CPTR(x) ((__attribute__((address_space(1))) const void*)(x))
#define LDS_PTR(x)     ((__attribute__((address_space(3))) void*)(x))

// ---------------------------------------------------------------------------
// MXFP4 quantize: fp32 -> packed E2M1 nibbles + E8M0 scale bytes.
// One 32-elem block per 8-lane group; 4 floats per lane.
// Data layout (16B chunks, chunk-major for conflict-free GEMM LDS reads):
//   chunk = (row>>8)*(K/32) + (k>>5); data byte = chunk*4096 + (row&255)*16
//           + ((k&31)>>1)
// Scale layout: byte = chunk*256 + (row&31)*8 + ((row>>5)&7)
// ---------------------------------------------------------------------------
__global__ __launch_bounds__(256) void mxfp4_quant_pack_kernel(
    const float* __restrict__ in, unsigned char* __restrict__ outq,
    unsigned char* __restrict__ outsc, int kshift, long long n) {
  long long e = ((long long)blockIdx.x * 256 + threadIdx.x) * 4;
  if (e >= n) return;

  float4 v = *reinterpret_cast<const float4*>(in + e);
  float am = fmaxf(fmaxf(fabsf(v.x), fabsf(v.y)), fmaxf(fabsf(v.z), fabsf(v.w)));
  am = fmaxf(am, __shfl_xor(am, 1, 64));
  am = fmaxf(am, __shfl_xor(am, 2, 64));
  am = fmaxf(am, __shfl_xor(am, 4, 64));

  float safe = am > 0.f ? am : 1.f;
  int se = ilogbf(safe) - 2;           // floor(log2(amax)) - E2M1_EMAX
  float inv = ldexpf(1.f, -se);

  float vv[4] = {v.x, v.y, v.z, v.w};
  unsigned int pack = 0;
#pragma unroll
  for (int j = 0; j < 4; ++j) {
    float val = vv[j] * inv;                 // exact (power-of-2)
    float av = fabsf(val);
    float avc = fmaxf(av, 9.765625e-4f);     // 2^-10 floor
    int ee = (int)((__float_as_uint(avc) >> 23) & 0xFF) - 127;  // floor(log2)
    ee = ee < 0 ? 0 : (ee > 2 ? 2 : ee);
    float step  = ldexpf(1.f, ee - 1);
    float istep = ldexpf(1.f, 1 - ee);
    float q = rintf(av * istep) * step;      // round-half-to-even, exact grid
    q = fminf(q, 6.f);
    // E2M1 code: {0,0.5,1,1.5,2,3,4,6} -> 0..7
    unsigned int c = q >= 5.f   ? 7u
                   : q >= 3.5f  ? 6u
                   : q >= 2.5f  ? 5u
                   : q >= 1.75f ? 4u
                   : q >= 1.25f ? 3u
                   : q >= 0.75f ? 2u
                   : q >= 0.25f ? 1u : 0u;
    if (val < 0.f) c |= 8u;                  // sign bit
    pack |= c << (4 * j);
  }

  const int K = 1 << kshift;
  const int row = (int)(e >> kshift);
  const int k = (int)(e & (K - 1));
  const size_t chunk = (size_t)(row >> 8) * (size_t)(1 << (kshift - 5)) + (k >> 5);
  *(ushort*)(outq + chunk * 4096 + (size_t)(row & 255) * 16 + ((k & 31) >> 1)) =
      (ushort)pack;
  if ((threadIdx.x & 7) == 0) {
    outsc[chunk * 256 + (row & 31) * 8 + ((row >> 5) & 7)] =
        (unsigned char)(se + 127);
  }
}

// ---------------------------------------------------------------------------
// MX-FP4 scaled GEMM: C[M][N] = dequant(A)*dequant(B)^T + bias
// via v_mfma_scale_f32_32x32x64_f8f6f4 (FMT=4 E2M1, E8M0 block scales).
// 256x256 tile, BK=128, 8 waves (2Mx4N, 128x64 out/wave), dbuf LDS (68KB),
// chunk-major LDS layout (zero bank conflicts), 1 barrier per K-tile,
// uniform 5 DMA loads/wave/K-tile, vmcnt(0) pre-satisfied by compute window.
// LDS buffer: [A data 16KB][B data 16KB][A sc 1KB][B sc 1KB] stride 34816.
// ---------------------------------------------------------------------------
#define BM 256
#define BN 256
#define NTHR 512
#define BUFS 34816

__global__ __launch_bounds__(NTHR, 2) void mxfp_gemm_kernel(
    const unsigned char* __restrict__ Aq, const unsigned char* __restrict__ Asc,
    const unsigned char* __restrict__ Bq, const unsigned char* __restrict__ Bsc,
    const float* __restrict__ bias, float* __restrict__ C,
    int M, int N, int K) {
  __shared__ unsigned char lds[2 * BUFS];  // 68 KiB

  const int tid = threadIdx.x;
  const int l   = tid & 63;
  const int wid = tid >> 6;
  const int wm  = wid >> 2;  // 0..1
  const int wn  = wid & 3;   // 0..3

  const int nwg = gridDim.x;       // multiple of 8
  const int bid = blockIdx.x;
  const int swz = (bid & 7) * (nwg >> 3) + (bid >> 3);
  const int nbn = N / BN;
  const int bm  = swz / nbn;
  const int bn  = swz % nbn;

  const int KC = K >> 5;  // 16B-chunks per row within a panel

  f32x16 acc[4][2] = {};

// stage one K-tile (BKT=128): per wave 2 A-data + 2 B-data + 1 scale chunk.
#define STAGE(BUFO, KT)                                                        \
  do {                                                                         \
    const int cl = wid & 3;                                                    \
    const int rg2 = (wid >> 2) << 1;                                           \
    const size_t abase = ((size_t)bm * KC + (size_t)(KT) * 4 + cl) * 4096;     \
    const size_t bbase = ((size_t)bn * KC + (size_t)(KT) * 4 + cl) * 4096;     \
    _Pragma("unroll") for (int i = 0; i < 2; ++i) {                            \
      __builtin_amdgcn_global_load_lds(                                        \
          GLOBAL_CPTR(Aq + abase + (rg2 + i) * 1024 + (l << 4)),               \
          LDS_PTR(lds + (BUFO) + cl * 4096 + (rg2 + i) * 1024), 16, 0, 0);     \
      __builtin_amdgcn_global_load_lds(                                        \
          GLOBAL_CPTR(Bq + bbase + (rg2 + i) * 1024 + (l << 4)),               \
          LDS_PTR(lds + (BUFO) + 16384 + cl * 4096 + (rg2 + i) * 1024),        \
          16, 0, 0);                                                           \
    }                                                                          \
    if (wid < 4) {                                                             \
      __builtin_amdgcn_global_load_lds(                                        \
          GLOBAL_CPTR(Asc + ((size_t)bm * KC + (size_t)(KT) * 4 + wid) * 256   \
                      + (l << 2)),                                             \
          LDS_PTR(lds + (BUFO) + 32768 + wid * 256), 4, 0, 0);                 \
    } else {                                                                   \
      __builtin_amdgcn_global_load_lds(                                        \
          GLOBAL_CPTR(Bsc + ((size_t)bn * KC + (size_t)(KT) * 4 + (wid - 4))   \
                      * 256 + (l << 2)),                                       \
          LDS_PTR(lds + (BUFO) + 33792 + (wid - 4) * 256), 4, 0, 0);           \
    }                                                                          \
  } while (0)

// compute one K-tile from buffer BUFO: 16 frag reads + 4 scale reads, 16 MFMA
#define KTILE(BUFO)                                                            \
  do {                                                                         \
    i32x4 ad[2][4];                                                            \
    i32x4 bd[2][2];                                                            \
    int asc[2], bsc[2];                                                        \
    _Pragma("unroll") for (int ks = 0; ks < 2; ++ks) {                         \
      const int cofs = (ks << 13) + ((l & 32) << 7); /* (2ks+(l>>5))*4096 */   \
      _Pragma("unroll") for (int mb = 0; mb < 4; ++mb)                         \
        ad[ks][mb] = *(const i32x4*)(lds + (BUFO) + cofs +                     \
                       (((wm << 7) + (mb << 5) + (l & 31)) << 4));             \
      _Pragma("unroll") for (int nb = 0; nb < 2; ++nb)                         \
        bd[ks][nb] = *(const i32x4*)(lds + (BUFO) + 16384 + cofs +             \
                       (((wn << 6) + (nb << 5) + (l & 31)) << 4));             \
      asc[ks] = *(const int*)(lds + (BUFO) + 32768 + (cofs >> 4) +             \
                              ((l & 31) << 3) + (wm << 2));                    \
      bsc[ks] = *(const ushort*)(lds + (BUFO) + 33792 + (cofs >> 4) +          \
                                 ((l & 31) << 3) + (wn << 1));                 \
    }                                                                          \
    _Pragma("unroll") for (int ks = 0; ks < 2; ++ks)                           \
      _Pragma("unroll") for (int mb = 0; mb < 4; ++mb) {                       \
        const int sa = (int)((unsigned)((asc[ks] >> (mb << 3)) & 255) *        \
                             0x01010101u);                                     \
        const i32x8 a8 = {ad[ks][mb][0], ad[ks][mb][1], ad[ks][mb][2],         \
                          ad[ks][mb][3], 0, 0, 0, 0};                          \
        _Pragma("unroll") for (int nb = 0; nb < 2; ++nb) {                     \
          const int sb = (int)((unsigned)((bsc[ks] >> (nb << 3)) & 255) *      \
                               0x01010101u);                                   \
          const i32x8 b8 = {bd[ks][nb][0], bd[ks][nb][1], bd[ks][nb][2],       \
                            bd[ks][nb][3], 0, 0, 0, 0};                        \
          acc[mb][nb] = __builtin_amdgcn_mfma_scale_f32_32x32x64_f8f6f4(       \
              a8, b8, acc[mb][nb], 4, 4, 0, sa, 0, sb);                        \
        }                                                                      \
      }                                                                        \
  } while (0)

  // prologue: tile0 -> buf0
  STAGE(0, 0);
  asm volatile("s_waitcnt vmcnt(0)" ::: "memory");
  __builtin_amdgcn_s_barrier();
  asm volatile("" ::: "memory");

  const int NKT = K >> 7;  // 128-wide K-tiles
  for (int t = 0; t < NKT; ++t) {
    const int tn = (t + 1 < NKT) ? (t + 1) : t;  // clamp -> dead buffer
    const int bufC = (t & 1) ? BUFS : 0;
    const int bufN = (t & 1) ? 0 : BUFS;
    STAGE(bufN, tn);       // issued first: full MFMA window to land
    KTILE(bufC);
    asm volatile("s_waitcnt vmcnt(0)" ::: "memory");  // 5 loads, pre-satisfied
    __builtin_amdgcn_s_barrier();
    asm volatile("" ::: "memory");
  }

  // epilogue: 32x32 C/D layout: col=lane&31, row=(reg&3)+8*(reg>>2)+4*(l>>5)
  const int colb = bn * BN + wn * 64 + (l & 31);
  const int rowb = bm * BM + wm * 128 + ((l >> 5) << 2);
  const float bv0 = bias[colb];
  const float bv1 = bias[colb + 32];
#pragma unroll
  for (int mb = 0; mb < 4; ++mb) {
#pragma unroll
    for (int nb = 0; nb < 2; ++nb) {
      const float bv = nb ? bv1 : bv0;
      const int col = colb + nb * 32;
#pragma unroll
      for (int r = 0; r < 16; ++r) {
        const int row = rowb + mb * 32 + ((r >> 2) << 3) + (r & 3);
        C[(size_t)row * N + col] = acc[mb][nb][r] + bv;
      }
    }
  }
}

// ---------------------------------------------------------------------------
extern "C" void kernel_launch(void* const* d_in, const int* in_sizes, int n_in,
                              void* d_out, int out_size, void* d_ws, size_t ws_size,
                              hipStream_t stream) {
  const float* x    = (const float*)d_in[0];  // [B,S,K] = [M,K]
  const float* w    = (const float*)d_in[1];  // [N,K]
  const float* bias = (const float*)d_in[2];  // [N]
  float* out = (float*)d_out;

  const int N = in_sizes[2];
  const int K = in_sizes[1] / N;
  const int M = (int)((long long)in_sizes[0] / K);
  const int kshift = __builtin_ctz(K);

  unsigned char* xq  = (unsigned char*)d_ws;               // M*K/2
  unsigned char* wq  = xq + ((size_t)M * K >> 1);          // N*K/2
  unsigned char* xsc = wq + ((size_t)N * K >> 1);          // M*K/32
  unsigned char* wsc = xsc + ((size_t)M * K >> 5);         // N*K/32

  const long long nx = (long long)M * K;
  const long long nw = (long long)N * K;

  mxfp4_quant_pack_kernel<<<dim3((unsigned)(nx / 1024)), dim3(256), 0, stream>>>(
      x, xq, xsc, kshift, nx);
  mxfp4_quant_pack_kernel<<<dim3((unsigned)(nw / 1024)), dim3(256), 0, stream>>>(
      w, wq, wsc, kshift, nw);

  dim3 grid((M / BM) * (N / BN));
  mxfp_gemm_kernel<<<grid, dim3(NTHR), 0, stream>>>(xq, xsc, wq, wsc, bias, out,
                                                    M, N, K);
}

// Round 7
// 151.687 us; speedup vs baseline: 2.5646x; 1.0186x over previous
//
#include <hip/hip_runtime.h>
#include <hip/hip_bf16.h>

typedef __attribute__((ext_vector_type(4))) int i32x4;
typedef __attribute__((ext_vector_type(8))) int i32x8;
typedef __attribute__((ext_vector_type(16))) float f32x16;

#define GLOBAL_CPTR(x) ((__attribute__((address_space(1))) const void*)(x))
#define LDS_PTR(x)     ((__attribute__((address_space(3))) void*)(x))

// ---------------------------------------------------------------------------
// MXFP4 quantize: fp32 -> packed E2M1 nibbles + E8M0 scale bytes.
// One 32-elem block per 4-lane group; 8 floats per lane.
// Data layout (16B chunks, chunk-major for conflict-free GEMM LDS reads):
//   chunk = (row>>8)*(K/32) + (k>>5); data byte = chunk*4096 + (row&255)*16
//           + ((k&31)>>1)
// Scale layout: byte = chunk*256 + (row&31)*8 + ((row>>5)&7)
// ---------------------------------------------------------------------------
__global__ __launch_bounds__(256) void mxfp4_quant_pack_kernel(
    const float* __restrict__ in, unsigned char* __restrict__ outq,
    unsigned char* __restrict__ outsc, int kshift, long long n) {
  long long e = ((long long)blockIdx.x * 256 + threadIdx.x) * 8;
  if (e >= n) return;

  float4 v0 = *reinterpret_cast<const float4*>(in + e);
  float4 v1 = *reinterpret_cast<const float4*>(in + e + 4);
  float vv[8] = {v0.x, v0.y, v0.z, v0.w, v1.x, v1.y, v1.z, v1.w};
  float am = 0.f;
#pragma unroll
  for (int j = 0; j < 8; ++j) am = fmaxf(am, fabsf(vv[j]));
  am = fmaxf(am, __shfl_xor(am, 1, 64));
  am = fmaxf(am, __shfl_xor(am, 2, 64));  // 4 lanes x 8 = 32-elem block

  float safe = am > 0.f ? am : 1.f;
  int se = ilogbf(safe) - 2;           // floor(log2(amax)) - E2M1_EMAX
  float inv = ldexpf(1.f, -se);

  unsigned int pack = 0;
#pragma unroll
  for (int j = 0; j < 8; ++j) {
    float val = vv[j] * inv;                 // exact (power-of-2)
    float av = fabsf(val);
    float avc = fmaxf(av, 9.765625e-4f);     // 2^-10 floor
    int ee = (int)((__float_as_uint(avc) >> 23) & 0xFF) - 127;  // floor(log2)
    ee = ee < 0 ? 0 : (ee > 2 ? 2 : ee);
    float step  = ldexpf(1.f, ee - 1);
    float istep = ldexpf(1.f, 1 - ee);
    float q = rintf(av * istep) * step;      // round-half-to-even, exact grid
    q = fminf(q, 6.f);
    // E2M1 code: {0,0.5,1,1.5,2,3,4,6} -> 0..7
    unsigned int c = q >= 5.f   ? 7u
                   : q >= 3.5f  ? 6u
                   : q >= 2.5f  ? 5u
                   : q >= 1.75f ? 4u
                   : q >= 1.25f ? 3u
                   : q >= 0.75f ? 2u
                   : q >= 0.25f ? 1u : 0u;
    if (val < 0.f) c |= 8u;                  // sign bit
    pack |= c << (4 * j);
  }

  const int row = (int)(e >> kshift);
  const int k = (int)(e & ((1 << kshift) - 1));
  const size_t chunk = (size_t)(row >> 8) * (size_t)(1 << (kshift - 5)) + (k >> 5);
  *(unsigned int*)(outq + chunk * 4096 + (size_t)(row & 255) * 16 +
                   ((k & 31) >> 1)) = pack;
  if ((threadIdx.x & 3) == 0) {
    outsc[chunk * 256 + (row & 31) * 8 + ((row >> 5) & 7)] =
        (unsigned char)(se + 127);
  }
}

// ---------------------------------------------------------------------------
// MX-FP4 scaled GEMM: C[M][N] = dequant(A)*dequant(B)^T + bias
// via v_mfma_scale_f32_32x32x64_f8f6f4 (FMT=4 E2M1, E8M0 block scales).
// 256x256 tile, BK=128, 8 waves (2Mx4N, 128x64 out/wave), dbuf LDS (68KB),
// chunk-major LDS layout (zero bank conflicts), 1 barrier per K-tile.
// Operand tuples a8/b8 built ONCE per (ks) via shufflevector concat with a
// hoisted zero quad -- removes the per-MFMA i32x8 rebuild mov flood (R6:
// VALUBusy 30% = ~2050 cyc/SIMD/K-tile of operand movs on the MFMA path).
// LDS buffer: [A data 16KB][B data 16KB][A sc 1KB][B sc 1KB] stride 34816.
// ---------------------------------------------------------------------------
#define BM 256
#define BN 256
#define NTHR 512
#define BUFS 34816

__global__ __launch_bounds__(NTHR, 2) void mxfp_gemm_kernel(
    const unsigned char* __restrict__ Aq, const unsigned char* __restrict__ Asc,
    const unsigned char* __restrict__ Bq, const unsigned char* __restrict__ Bsc,
    const float* __restrict__ bias, float* __restrict__ C,
    int M, int N, int K) {
  __shared__ unsigned char lds[2 * BUFS];  // 68 KiB

  const int tid = threadIdx.x;
  const int l   = tid & 63;
  const int wid = tid >> 6;
  const int wm  = wid >> 2;  // 0..1
  const int wn  = wid & 3;   // 0..3

  const int nwg = gridDim.x;       // multiple of 8
  const int bid = blockIdx.x;
  const int swz = (bid & 7) * (nwg >> 3) + (bid >> 3);
  const int nbn = N / BN;
  const int bm  = swz / nbn;
  const int bn  = swz % nbn;

  const int KC = K >> 5;  // 16B-chunks per row within a panel

  f32x16 acc[4][2] = {};

// stage one K-tile (BKT=128): per wave 2 A-data + 2 B-data + 1 scale chunk.
#define STAGE(BUFO, KT)                                                        \
  do {                                                                         \
    const int cl = wid & 3;                                                    \
    const int rg2 = (wid >> 2) << 1;                                           \
    const size_t abase = ((size_t)bm * KC + (size_t)(KT) * 4 + cl) * 4096;     \
    const size_t bbase = ((size_t)bn * KC + (size_t)(KT) * 4 + cl) * 4096;     \
    _Pragma("unroll") for (int i = 0; i < 2; ++i) {                            \
      __builtin_amdgcn_global_load_lds(                                        \
          GLOBAL_CPTR(Aq + abase + (rg2 + i) * 1024 + (l << 4)),               \
          LDS_PTR(lds + (BUFO) + cl * 4096 + (rg2 + i) * 1024), 16, 0, 0);     \
      __builtin_amdgcn_global_load_lds(                                        \
          GLOBAL_CPTR(Bq + bbase + (rg2 + i) * 1024 + (l << 4)),               \
          LDS_PTR(lds + (BUFO) + 16384 + cl * 4096 + (rg2 + i) * 1024),        \
          16, 0, 0);                                                           \
    }                                                                          \
    if (wid < 4) {                                                             \
      __builtin_amdgcn_global_load_lds(                                        \
          GLOBAL_CPTR(Asc + ((size_t)bm * KC + (size_t)(KT) * 4 + wid) * 256   \
                      + (l << 2)),                                             \
          LDS_PTR(lds + (BUFO) + 32768 + wid * 256), 4, 0, 0);                 \
    } else {                                                                   \
      __builtin_amdgcn_global_load_lds(                                        \
          GLOBAL_CPTR(Bsc + ((size_t)bn * KC + (size_t)(KT) * 4 + (wid - 4))   \
                      * 256 + (l << 2)),                                       \
          LDS_PTR(lds + (BUFO) + 33792 + (wid - 4) * 256), 4, 0, 0);           \
    }                                                                          \
  } while (0)

// compute one K-tile from buffer BUFO: per ks-half, build 6 operand tuples
// + 6 replicated scales ONCE, then 8 MFMA using them.
#define KTILE(BUFO)                                                            \
  do {                                                                         \
    const i32x4 z4 = {0, 0, 0, 0};                                             \
    _Pragma("unroll") for (int ks = 0; ks < 2; ++ks) {                         \
      const int cofs = (ks << 13) + ((l & 32) << 7); /* (2ks+(l>>5))*4096 */   \
      i32x8 a8[4], b8[2];                                                      \
      int sa[4], sb[2];                                                        \
      _Pragma("unroll") for (int mb = 0; mb < 4; ++mb)                         \
        a8[mb] = __builtin_shufflevector(                                      \
            *(const i32x4*)(lds + (BUFO) + cofs +                              \
                            (((wm << 7) + (mb << 5) + (l & 31)) << 4)),        \
            z4, 0, 1, 2, 3, 4, 5, 6, 7);                                       \
      _Pragma("unroll") for (int nb = 0; nb < 2; ++nb)                         \
        b8[nb] = __builtin_shufflevector(                                      \
            *(const i32x4*)(lds + (BUFO) + 16384 + cofs +                      \
                            (((wn << 6) + (nb << 5) + (l & 31)) << 4)),        \
            z4, 0, 1, 2, 3, 4, 5, 6, 7);                                       \
      const int av = *(const int*)(lds + (BUFO) + 32768 + (cofs >> 4) +        \
                                   ((l & 31) << 3) + (wm << 2));               \
      const int bv = *(const ushort*)(lds + (BUFO) + 33792 + (cofs >> 4) +     \
                                      ((l & 31) << 3) + (wn << 1));            \
      _Pragma("unroll") for (int mb = 0; mb < 4; ++mb)                         \
        sa[mb] = (int)((unsigned)((av >> (mb << 3)) & 255) * 0x01010101u);     \
      _Pragma("unroll") for (int nb = 0; nb < 2; ++nb)                         \
        sb[nb] = (int)((unsigned)((bv >> (nb << 3)) & 255) * 0x01010101u);     \
      _Pragma("unroll") for (int mb = 0; mb < 4; ++mb)                         \
        _Pragma("unroll") for (int nb = 0; nb < 2; ++nb)                       \
          acc[mb][nb] = __builtin_amdgcn_mfma_scale_f32_32x32x64_f8f6f4(       \
              a8[mb], b8[nb], acc[mb][nb], 4, 4, 0, sa[mb], 0, sb[nb]);        \
    }                                                                          \
  } while (0)

  // prologue: tile0 -> buf0
  STAGE(0, 0);
  asm volatile("s_waitcnt vmcnt(0)" ::: "memory");
  __builtin_amdgcn_s_barrier();
  asm volatile("" ::: "memory");

  const int NKT = K >> 7;  // 128-wide K-tiles
  for (int t = 0; t < NKT; ++t) {
    const int tn = (t + 1 < NKT) ? (t + 1) : t;  // clamp -> dead buffer
    const int bufC = (t & 1) ? BUFS : 0;
    const int bufN = (t & 1) ? 0 : BUFS;
    STAGE(bufN, tn);       // issued first: full MFMA window to land
    KTILE(bufC);
    asm volatile("s_waitcnt vmcnt(0)" ::: "memory");  // 5 loads, pre-satisfied
    __builtin_amdgcn_s_barrier();
    asm volatile("" ::: "memory");
  }

  // epilogue: 32x32 C/D layout: col=lane&31, row=(reg&3)+8*(reg>>2)+4*(l>>5)
  const int colb = bn * BN + wn * 64 + (l & 31);
  const int rowb = bm * BM + wm * 128 + ((l >> 5) << 2);
  const float bv0 = bias[colb];
  const float bv1 = bias[colb + 32];
#pragma unroll
  for (int mb = 0; mb < 4; ++mb) {
#pragma unroll
    for (int nb = 0; nb < 2; ++nb) {
      const float bv = nb ? bv1 : bv0;
      const int col = colb + nb * 32;
#pragma unroll
      for (int r = 0; r < 16; ++r) {
        const int row = rowb + mb * 32 + ((r >> 2) << 3) + (r & 3);
        C[(size_t)row * N + col] = acc[mb][nb][r] + bv;
      }
    }
  }
}

// ---------------------------------------------------------------------------
extern "C" void kernel_launch(void* const* d_in, const int* in_sizes, int n_in,
                              void* d_out, int out_size, void* d_ws, size_t ws_size,
                              hipStream_t stream) {
  const float* x    = (const float*)d_in[0];  // [B,S,K] = [M,K]
  const float* w    = (const float*)d_in[1];  // [N,K]
  const float* bias = (const float*)d_in[2];  // [N]
  float* out = (float*)d_out;

  const int N = in_sizes[2];
  const int K = in_sizes[1] / N;
  const int M = (int)((long long)in_sizes[0] / K);
  const int kshift = __builtin_ctz(K);

  unsigned char* xq  = (unsigned char*)d_ws;               // M*K/2
  unsigned char* wq  = xq + ((size_t)M * K >> 1);          // N*K/2
  unsigned char* xsc = wq + ((size_t)N * K >> 1);          // M*K/32
  unsigned char* wsc = xsc + ((size_t)M * K >> 5);         // N*K/32

  const long long nx = (long long)M * K;
  const long long nw = (long long)N * K;

  mxfp4_quant_pack_kernel<<<dim3((unsigned)(nx / 2048)), dim3(256), 0, stream>>>(
      x, xq, xsc, kshift, nx);
  mxfp4_quant_pack_kernel<<<dim3((unsigned)(nw / 2048)), dim3(256), 0, stream>>>(
      w, wq, wsc, kshift, nw);

  dim3 grid((M / BM) * (N / BN));
  mxfp_gemm_kernel<<<grid, dim3(NTHR), 0, stream>>>(xq, xsc, wq, wsc, bias, out,
                                                    M, N, K);
}